// Round 6
// baseline (95.441 us; speedup 1.0000x reference)
//
#include <hip/hip_runtime.h>

// Problem constants (x: [128, 65536] fp32, LEVEL=8)
static constexpr int BROWS = 128;   // batch rows
static constexpr int T     = 65536; // samples per row
static constexpr int CL    = 256;   // chunk length = 2^LEVEL
static constexpr int NCH   = 256;   // chunks per row = T / CL (positions per node)
static constexpr int NODES = 256;   // 2^LEVEL leaves
static constexpr int KG    = 32;    // chunks per phase
static constexpr int NPH   = NCH / KG; // 8 phases per row
static constexpr int LSTR  = 257;   // padded LDS row stride (breaks bank conflicts)
static constexpr int NTHR  = 1024;  // 16 waves per block

// Output row for Hadamard-order index h (in-place FWHT leaves Hadamard order):
//   c_nat[n] = H[bitrev8(n)], freq perm out[m] = c_nat[gray^-1(m)] => m = gray(bitrev8(h))
__device__ __forceinline__ int freq_pos(int h) {
    unsigned r = __brev((unsigned)h) >> 24; // bitrev8
    return (int)(r ^ (r >> 1));             // gray code
}

__device__ __forceinline__ void bfly01(float4& v) {
    // FWHT stages on j-bits 0,1 (within the float4)
    float4 w;
    w.x = v.x + v.y; w.y = v.x - v.y;
    w.z = v.z + v.w; w.w = v.z - v.w;
    v.x = w.x + w.z; v.z = w.x - w.z;
    v.y = w.y + w.w; v.w = w.y - w.w;
}

// Lane-exchange via DPP (VALU pipe — no LDS traffic). HW-validated.
// xor1 = quad_perm [1,0,3,2] = 0xB1; xor2 = quad_perm [2,3,0,1] = 0x4E;
// xor8 = row_ror:8 = 0x128 ((i+8)%16 == i^8 within a 16-lane row).
template<int CTRL>
__device__ __forceinline__ float xchg_dpp(float v) {
    return __builtin_bit_cast(float,
        __builtin_amdgcn_update_dpp(0, __builtin_bit_cast(int, v), CTRL, 0xF, 0xF, true));
}

template<int CTRL>
__device__ __forceinline__ void stage_dpp(float4& v1, float4& v2, float sgn) {
    float o;
    o = xchg_dpp<CTRL>(v1.x); v1.x = fmaf(sgn, v1.x, o);
    o = xchg_dpp<CTRL>(v1.y); v1.y = fmaf(sgn, v1.y, o);
    o = xchg_dpp<CTRL>(v1.z); v1.z = fmaf(sgn, v1.z, o);
    o = xchg_dpp<CTRL>(v1.w); v1.w = fmaf(sgn, v1.w, o);
    o = xchg_dpp<CTRL>(v2.x); v2.x = fmaf(sgn, v2.x, o);
    o = xchg_dpp<CTRL>(v2.y); v2.y = fmaf(sgn, v2.y, o);
    o = xchg_dpp<CTRL>(v2.z); v2.z = fmaf(sgn, v2.z, o);
    o = xchg_dpp<CTRL>(v2.w); v2.w = fmaf(sgn, v2.w, o);
}

__device__ __forceinline__ void stage_shfl(float4& v1, float4& v2, float sgn, int mask) {
    float o;
    o = __shfl_xor(v1.x, mask, 64); v1.x = fmaf(sgn, v1.x, o);
    o = __shfl_xor(v1.y, mask, 64); v1.y = fmaf(sgn, v1.y, o);
    o = __shfl_xor(v1.z, mask, 64); v1.z = fmaf(sgn, v1.z, o);
    o = __shfl_xor(v1.w, mask, 64); v1.w = fmaf(sgn, v1.w, o);
    o = __shfl_xor(v2.x, mask, 64); v2.x = fmaf(sgn, v2.x, o);
    o = __shfl_xor(v2.y, mask, 64); v2.y = fmaf(sgn, v2.y, o);
    o = __shfl_xor(v2.z, mask, 64); v2.z = fmaf(sgn, v2.z, o);
    o = __shfl_xor(v2.w, mask, 64); v2.w = fmaf(sgn, v2.w, o);
}

// 256 blocks = (row b, half h). Each block FWHTs ALL 256 chunks of row b
// (duplicate compute is ~free: whole-problem FWHT VALU ≈ 2 µs machine-wide)
// so the entropy sum is block-local — but only scatters/transposes/stores
// coeffs for its own 128 chunks (phases 4h..4h+3). Unowned phases are pure
// register work: no LDS, no barrier. 4 barriers total; full 256-CU machine;
// ONE dispatch, no workspace, no fences, no atomics.
// Both siblings accumulate phases in the same order 0..7 -> bitwise-identical
// entropy/keep; h=0 writes them; each block zeroes its own half on !keep.
__global__ __launch_bounds__(NTHR, 4) void wht_half(const float* __restrict__ x,
                                                    float* __restrict__ coeffs,
                                                    float* __restrict__ entropy,
                                                    float* __restrict__ keep) {
    __shared__ float lds[2][KG][LSTR]; // 65.8 KB; buf0 reused as 16x2x256 partials later

    const int b    = blockIdx.x >> 1;  // batch row
    const int h    = blockIdx.x & 1;   // which half of the row this block OWNS
    const int tid  = threadIdx.x;
    const int lane = tid & 63;
    const int wave = tid >> 6;         // 0..15
    const int half = lane >> 5;        // which of 2 concurrent chunks
    const int L    = lane & 31;        // position within chunk (j-bits 2..6)

    const float* xb = x + (size_t)b * T;

    // lane owns the SAME 8 nodes (h = 4L+i and 128+4L+i) in every chunk
    int npos1[4], npos2[4];
    #pragma unroll
    for (int i = 0; i < 4; ++i) {
        npos1[i] = freq_pos(4 * L + i);
        npos2[i] = freq_pos(128 + 4 * L + i);
    }
    float A1[4] = {0.f,0.f,0.f,0.f}, B1[4] = {0.f,0.f,0.f,0.f};
    float A2[4] = {0.f,0.f,0.f,0.f}, B2[4] = {0.f,0.f,0.f,0.f};

    // Butterfly signs for the 5 cross-lane stages (loop-invariant)
    const float sgn0 = 1.0f - 2.0f * (float)((L >> 0) & 1);
    const float sgn1 = 1.0f - 2.0f * (float)((L >> 1) & 1);
    const float sgn2 = 1.0f - 2.0f * (float)((L >> 2) & 1);
    const float sgn3 = 1.0f - 2.0f * (float)((L >> 3) & 1);
    const float sgn4 = 1.0f - 2.0f * (float)((L >> 4) & 1);

    const int kl  = wave * 2 + half; // chunk index within phase (0..31)
    const int col = 4 * L;

    // Preload phase 0 (prefetch depth 1 across phases)
    float4 va = *(const float4*)(xb + (size_t)kl * CL + col);
    float4 vb = *(const float4*)(xb + (size_t)kl * CL + col + 128);

    // Transpose-write indexing (constant across phases)
    const int kk = (tid & 7) * 4; // k offset within phase (0,4,...,28)
    const int m0 = tid >> 3;      // 0..127

    #pragma unroll
    for (int ph = 0; ph < NPH; ++ph) {
        // Issue next phase's loads first — they retire under this phase's compute
        float4 na, nb;
        if (ph + 1 < NPH) {
            const float* q = xb + (size_t)((ph + 1) * KG + kl) * CL + col;
            na = *(const float4*)(q);
            nb = *(const float4*)(q + 128);
        }

        float4 v1 = va, v2 = vb;

        // FWHT stage j-bit7 (across the two registers, pure VALU)
        float4 t;
        t.x = v1.x - v2.x; t.y = v1.y - v2.y; t.z = v1.z - v2.z; t.w = v1.w - v2.w;
        v1.x += v2.x; v1.y += v2.y; v1.z += v2.z; v1.w += v2.w;
        v2 = t;

        bfly01(v1);
        bfly01(v2);

        // FWHT stages j-bits 2..6 = lane xor 1,2,4,8,16
        stage_dpp<0xB1>(v1, v2, sgn0);   // xor 1
        stage_dpp<0x4E>(v1, v2, sgn1);   // xor 2
        stage_shfl(v1, v2, sgn2, 4);     // xor 4
        stage_dpp<0x128>(v1, v2, sgn3);  // xor 8
        stage_shfl(v1, v2, sgn4, 16);    // xor 16

        // scale by (1/sqrt2)^8 = 1/16; entropy partials (EVERY phase, so the
        // whole row's sum is block-local)
        float c1r[4] = {v1.x*0.0625f, v1.y*0.0625f, v1.z*0.0625f, v1.w*0.0625f};
        float c2r[4] = {v2.x*0.0625f, v2.y*0.0625f, v2.z*0.0625f, v2.w*0.0625f};
        #pragma unroll
        for (int i = 0; i < 4; ++i) {
            const float s1 = c1r[i] * c1r[i];
            A1[i] += s1;
            B1[i] += s1 * __logf(s1 + 1e-35f); // c=0 -> term 0
            const float s2 = c2r[i] * c2r[i];
            A2[i] += s2;
            B2[i] += s2 * __logf(s2 + 1e-35f);
        }

        // Owned phases only: freq-ordered LDS scatter + transposed coeffs write.
        // Block-uniform branch (h is uniform) -> barrier inside is legal.
        if ((ph >> 2) == h) {
            const int buf = ph & 1; // owned phases are consecutive: bufs 0,1,0,1
            #pragma unroll
            for (int i = 0; i < 4; ++i) {
                lds[buf][kl][npos1[i]] = c1r[i];
                lds[buf][kl][npos2[i]] = c2r[i];
            }
            __syncthreads(); // scatter[buf] complete -> transpose-read[buf]

            // coeffs[b][m][ph*KG + kk .. kk+3]; 1024 threads = 128 m x 8 kk per pass
            float* ob = coeffs + (size_t)b * T + ph * KG;
            #pragma unroll
            for (int p = 0; p < 2; ++p) {
                const int m = p * 128 + m0;
                float4 v;
                v.x = lds[buf][kk + 0][m];
                v.y = lds[buf][kk + 1][m];
                v.z = lds[buf][kk + 2][m];
                v.w = lds[buf][kk + 3][m];
                *(float4*)(ob + (size_t)m * NCH + kk) = v;
            }
            // No second barrier: next owned phase scatters buf^1; its barrier
            // orders this phase's reads (program-order) against the buf reuse.
        }

        va = na; vb = nb;
    }

    // ---- entropy finalize, fully in-block ----
    // Merge the two lane-halves (same node sets)
    #pragma unroll
    for (int i = 0; i < 4; ++i) {
        A1[i] += __shfl_xor(A1[i], 32, 64); B1[i] += __shfl_xor(B1[i], 32, 64);
        A2[i] += __shfl_xor(A2[i], 32, 64); B2[i] += __shfl_xor(B2[i], 32, 64);
    }
    // Partials go in buf0 (8224 floats >= 16*512 = 8192). Last owned phase used
    // buf1; the last buf0 reads were ordered by the subsequent owned barrier.
    float* pl = &lds[0][0][0];
    if (half == 0) {
        #pragma unroll
        for (int i = 0; i < 4; ++i) {
            pl[wave * 512 + npos1[i]]       = A1[i];
            pl[wave * 512 + 256 + npos1[i]] = B1[i];
            pl[wave * 512 + npos2[i]]       = A2[i];
            pl[wave * 512 + 256 + npos2[i]] = B2[i];
        }
    }
    __syncthreads();

    // Sum the 16 wave-partials; columns are thread-private
    if (tid < 512) {
        float s = 0.f;
        #pragma unroll
        for (int w = 0; w < 16; ++w) s += pl[w * 512 + tid];
        pl[tid] = s;
    }
    __syncthreads();

    if (tid < NODES) {
        const float A = pl[tid];
        const float B = pl[256 + tid];
        const float S = A + 1e-8f;
        const float e = (A * __logf(S) - B) / S;
        const bool kp = e > 0.1f;

        if (h == 0) { // siblings compute bitwise-identical e/kp; one writer
            entropy[b * NODES + tid] = e;
            keep[b * NODES + tid]    = kp ? 1.0f : 0.0f;
        }

        // Rare path (never fires for Gaussian input): zero OUR half of the row.
        if (!kp) {
            float4 z = make_float4(0.f, 0.f, 0.f, 0.f);
            float4* cp = (float4*)(coeffs + ((size_t)b * NODES + tid) * NCH + h * (NCH / 2));
            #pragma unroll
            for (int j = 0; j < NCH / 8; ++j) cp[j] = z;
        }
    }
}

extern "C" void kernel_launch(void* const* d_in, const int* in_sizes, int n_in,
                              void* d_out, int out_size, void* d_ws, size_t ws_size,
                              hipStream_t stream) {
    const float* x = (const float*)d_in[0];

    float* coeffs  = (float*)d_out;                         // [128][256][256]
    float* entropy = coeffs + (size_t)BROWS * NODES * NCH;  // [128][256]
    float* keepf   = entropy + (size_t)BROWS * NODES;       // [128][256] as 0/1 float

    (void)d_ws; (void)ws_size; // no workspace — single dispatch

    wht_half<<<dim3(BROWS * 2), dim3(NTHR), 0, stream>>>(x, coeffs, entropy, keepf);
}

// Round 7
// 84.050 us; speedup vs baseline: 1.1355x; 1.1355x over previous
//
#include <hip/hip_runtime.h>

// Problem constants (x: [128, 65536] fp32, LEVEL=8)
static constexpr int BROWS = 128;   // batch rows
static constexpr int T     = 65536; // samples per row
static constexpr int CL    = 256;   // chunk length = 2^LEVEL
static constexpr int NCH   = 256;   // chunks per row = T / CL (positions per node)
static constexpr int NODES = 256;   // 2^LEVEL leaves
static constexpr int KG    = 16;    // chunks handled per block (2048 blocks, 8/CU)
static constexpr int NGRP  = NCH / KG; // 16 chunk-groups per row
static constexpr int LSTR  = 257;   // padded LDS row stride (breaks bank conflicts)

// Output row for Hadamard-order index h (in-place FWHT leaves Hadamard order):
//   c_nat[n] = H[bitrev8(n)], freq perm out[m] = c_nat[gray^-1(m)] => m = gray(bitrev8(h))
__device__ __forceinline__ int freq_pos(int h) {
    unsigned r = __brev((unsigned)h) >> 24; // bitrev8
    return (int)(r ^ (r >> 1));             // gray code
}

__device__ __forceinline__ void bfly01(float4& v) {
    // FWHT stages on j-bits 0,1 (within the float4)
    float4 w;
    w.x = v.x + v.y; w.y = v.x - v.y;
    w.z = v.z + v.w; w.w = v.z - v.w;
    v.x = w.x + w.z; v.z = w.x - w.z;
    v.y = w.y + w.w; v.w = w.y - w.w;
}

// Lane-exchange via DPP (VALU pipe — no LDS traffic). HW-validated.
// xor1 = quad_perm [1,0,3,2] = 0xB1; xor2 = quad_perm [2,3,0,1] = 0x4E;
// xor8 = row_ror:8 = 0x128 ((i+8)%16 == i^8 within a 16-lane row).
template<int CTRL>
__device__ __forceinline__ float xchg_dpp(float v) {
    return __builtin_bit_cast(float,
        __builtin_amdgcn_update_dpp(0, __builtin_bit_cast(int, v), CTRL, 0xF, 0xF, true));
}

template<int CTRL>
__device__ __forceinline__ void stage_dpp(float4& v1, float4& v2, float sgn) {
    float o;
    o = xchg_dpp<CTRL>(v1.x); v1.x = fmaf(sgn, v1.x, o);
    o = xchg_dpp<CTRL>(v1.y); v1.y = fmaf(sgn, v1.y, o);
    o = xchg_dpp<CTRL>(v1.z); v1.z = fmaf(sgn, v1.z, o);
    o = xchg_dpp<CTRL>(v1.w); v1.w = fmaf(sgn, v1.w, o);
    o = xchg_dpp<CTRL>(v2.x); v2.x = fmaf(sgn, v2.x, o);
    o = xchg_dpp<CTRL>(v2.y); v2.y = fmaf(sgn, v2.y, o);
    o = xchg_dpp<CTRL>(v2.z); v2.z = fmaf(sgn, v2.z, o);
    o = xchg_dpp<CTRL>(v2.w); v2.w = fmaf(sgn, v2.w, o);
}

__device__ __forceinline__ void stage_shfl(float4& v1, float4& v2, float sgn, int mask) {
    float o;
    o = __shfl_xor(v1.x, mask, 64); v1.x = fmaf(sgn, v1.x, o);
    o = __shfl_xor(v1.y, mask, 64); v1.y = fmaf(sgn, v1.y, o);
    o = __shfl_xor(v1.z, mask, 64); v1.z = fmaf(sgn, v1.z, o);
    o = __shfl_xor(v1.w, mask, 64); v1.w = fmaf(sgn, v1.w, o);
    o = __shfl_xor(v2.x, mask, 64); v2.x = fmaf(sgn, v2.x, o);
    o = __shfl_xor(v2.y, mask, 64); v2.y = fmaf(sgn, v2.y, o);
    o = __shfl_xor(v2.z, mask, 64); v2.z = fmaf(sgn, v2.z, o);
    o = __shfl_xor(v2.w, mask, 64); v2.w = fmaf(sgn, v2.w, o);
}

// Per block: 16 chunks of one batch row -> 256-pt FWHT (dual-chunk wave layout)
// -> freq-ordered transposed coeffs write + per-node entropy partials into ws.
// BYTE-IDENTICAL to the R2 kernel (13.5 µs marginal cost, measured R4-R2).
__global__ __launch_bounds__(256) void wht_kernel(const float* __restrict__ x,
                                                  float* __restrict__ coeffs,
                                                  float* __restrict__ part) {
    __shared__ float lds[KG][LSTR]; // 16.5 KB; reused as 4x2x256 partial buffer later

    const int b    = blockIdx.x >> 4;  // 16 chunk-groups per row
    const int kg   = blockIdx.x & 15;
    const int k0   = kg * KG;
    const int lane = threadIdx.x & 63;
    const int wave = threadIdx.x >> 6; // 4 waves
    const int half = lane >> 5;        // which of 2 concurrent chunks
    const int L    = lane & 31;        // position within chunk (j-bits 2..6)

    const float* xb = x + (size_t)b * T;

    // lane owns the SAME 8 nodes (h = 4L+i and 128+4L+i) in every chunk
    int npos1[4], npos2[4];
    #pragma unroll
    for (int i = 0; i < 4; ++i) {
        npos1[i] = freq_pos(4 * L + i);
        npos2[i] = freq_pos(128 + 4 * L + i);
    }
    float A1[4] = {0.f,0.f,0.f,0.f}, B1[4] = {0.f,0.f,0.f,0.f};
    float A2[4] = {0.f,0.f,0.f,0.f}, B2[4] = {0.f,0.f,0.f,0.f};

    // Butterfly signs for the 5 cross-lane stages (loop-invariant)
    const float sgn0 = 1.0f - 2.0f * (float)((L >> 0) & 1);
    const float sgn1 = 1.0f - 2.0f * (float)((L >> 1) & 1);
    const float sgn2 = 1.0f - 2.0f * (float)((L >> 2) & 1);
    const float sgn3 = 1.0f - 2.0f * (float)((L >> 3) & 1);
    const float sgn4 = 1.0f - 2.0f * (float)((L >> 4) & 1);

    // Each wave handles 4 chunks as 2 iterations x 2 chunks (one per lane-half)
    #pragma unroll
    for (int it = 0; it < 2; ++it) {
        const int kl = wave * 4 + it * 2 + half; // local chunk row in LDS (0..15)
        const float* cp = xb + (size_t)(k0 + kl) * CL + 4 * L;
        float4 v1 = *(const float4*)(cp);        // j = 4L+i      (bit7=0)
        float4 v2 = *(const float4*)(cp + 128);  // j = 128+4L+i  (bit7=1)

        // FWHT stage j-bit7 (across the two registers, pure VALU)
        float4 t;
        t.x = v1.x - v2.x; t.y = v1.y - v2.y; t.z = v1.z - v2.z; t.w = v1.w - v2.w;
        v1.x += v2.x; v1.y += v2.y; v1.z += v2.z; v1.w += v2.w;
        v2 = t;

        // FWHT stages j-bits 0,1 (intra-float4)
        bfly01(v1);
        bfly01(v2);

        // FWHT stages j-bits 2..6 = lane xor 1,2,4,8,16.
        // Masks 1,2,8 run on the VALU via DPP; masks 4,16 stay on the LDS pipe.
        stage_dpp<0xB1>(v1, v2, sgn0);   // xor 1  (quad_perm [1,0,3,2])
        stage_dpp<0x4E>(v1, v2, sgn1);   // xor 2  (quad_perm [2,3,0,1])
        stage_shfl(v1, v2, sgn2, 4);     // xor 4  (ds_swizzle)
        stage_dpp<0x128>(v1, v2, sgn3);  // xor 8  (row_ror:8)
        stage_shfl(v1, v2, sgn4, 16);    // xor 16 (ds_swizzle)

        // scale by (1/sqrt2)^8 = 1/16; accumulate entropy partials; LDS scatter
        float c1[4] = {v1.x*0.0625f, v1.y*0.0625f, v1.z*0.0625f, v1.w*0.0625f};
        float c2[4] = {v2.x*0.0625f, v2.y*0.0625f, v2.z*0.0625f, v2.w*0.0625f};
        #pragma unroll
        for (int i = 0; i < 4; ++i) {
            const float s1 = c1[i] * c1[i];
            A1[i] += s1;
            B1[i] += s1 * __logf(s1 + 1e-35f); // c=0 -> term 0, matches p*log(p+eps)
            lds[kl][npos1[i]] = c1[i];
            const float s2 = c2[i] * c2[i];
            A2[i] += s2;
            B2[i] += s2 * __logf(s2 + 1e-35f);
            lds[kl][npos2[i]] = c2[i];
        }
    }
    __syncthreads();

    // Transposed, coalesced write: coeffs[b][m][k0 + kk .. kk+3]
    // Wave writes 16 node-rows x 64 B (aligned 64-B sectors, no RMW).
    float* ob = coeffs + (size_t)b * T + k0;
    const int kk = (threadIdx.x & 3) * 4; // k offset within group (0,4,8,12)
    const int m0 = threadIdx.x >> 2;      // 0..63
    #pragma unroll
    for (int p = 0; p < 4; ++p) {
        const int m = p * 64 + m0;
        float4 v;
        v.x = lds[kk + 0][m];
        v.y = lds[kk + 1][m];
        v.z = lds[kk + 2][m];
        v.w = lds[kk + 3][m];
        *(float4*)(ob + (size_t)m * NCH + kk) = v;
    }
    __syncthreads();

    // Merge the two lane-halves (same node sets), then cross-wave reduce via LDS
    #pragma unroll
    for (int i = 0; i < 4; ++i) {
        A1[i] += __shfl_xor(A1[i], 32, 64); B1[i] += __shfl_xor(B1[i], 32, 64);
        A2[i] += __shfl_xor(A2[i], 32, 64); B2[i] += __shfl_xor(B2[i], 32, 64);
    }
    float* pl = &lds[0][0]; // need 4*512 = 2048 floats, have 16*257 = 4112
    if (half == 0) {
        #pragma unroll
        for (int i = 0; i < 4; ++i) {
            pl[wave * 512 + npos1[i]]       = A1[i];
            pl[wave * 512 + 256 + npos1[i]] = B1[i];
            pl[wave * 512 + npos2[i]]       = A2[i];
            pl[wave * 512 + 256 + npos2[i]] = B2[i];
        }
    }
    __syncthreads();

    const int n = threadIdx.x; // 0..255 = node
    const float A = pl[n] + pl[512 + n] + pl[1024 + n] + pl[1536 + n];
    const float B = pl[256 + n] + pl[768 + n] + pl[1280 + n] + pl[1792 + n];
    float* pp = part + (size_t)blockIdx.x * 512;
    pp[n]       = A;
    pp[256 + n] = B;
}

// RESTRUCTURED finalize: 512 blocks x 256 threads (8 waves/CU machine-wide,
// 4x the old wave count; old: 128 blocks = 2 waves/CU on half the CUs).
// Block handles 64 rows; the 16-group reduction is split 4 groups/thread
// across the 4 waves; loads stay fully coalesced (lane index = consecutive n);
// tiny LDS tree combines the 4 wave-partials; wave 0 does the entropy epilogue.
__global__ __launch_bounds__(256) void finalize_kernel(const float* __restrict__ part,
                                                       float* __restrict__ coeffs,
                                                       float* __restrict__ entropy,
                                                       float* __restrict__ keep) {
    __shared__ float pA[4][64], pB[4][64];

    const int gq   = threadIdx.x >> 6; // wave 0..3 -> groups gq*4 .. gq*4+3
    const int lane = threadIdx.x & 63;
    const int row0 = blockIdx.x * 64;  // 64 rows per block, all within one b
    const int row  = row0 + lane;      // this lane's (b, n)
    const int b    = row >> 8;
    const int n    = row & 255;

    float A = 0.f, B = 0.f;
    #pragma unroll
    for (int j = 0; j < 4; ++j) {
        const int g = gq * 4 + j;
        const float* p = part + (size_t)(b * NGRP + g) * 512;
        A += p[n];        // lanes: consecutive n -> coalesced 256B
        B += p[256 + n];
    }
    pA[gq][lane] = A;
    pB[gq][lane] = B;
    __syncthreads();

    if (threadIdx.x < 64) {
        A = pA[0][lane] + pA[1][lane] + pA[2][lane] + pA[3][lane];
        B = pB[0][lane] + pB[1][lane] + pB[2][lane] + pB[3][lane];

        const float S = A + 1e-8f;
        const float e = (A * __logf(S) - B) / S;
        const bool kp = e > 0.1f;

        entropy[row] = e;
        keep[row]    = kp ? 1.0f : 0.0f;

        // Rare path (never fires for Gaussian input): zero this node's coeff row.
        if (!kp) {
            float4 z = make_float4(0.f, 0.f, 0.f, 0.f);
            float4* cp = (float4*)(coeffs + (size_t)row * NCH);
            for (int j = 0; j < NCH / 4; ++j) cp[j] = z;
        }
    }
}

extern "C" void kernel_launch(void* const* d_in, const int* in_sizes, int n_in,
                              void* d_out, int out_size, void* d_ws, size_t ws_size,
                              hipStream_t stream) {
    const float* x = (const float*)d_in[0];

    float* coeffs  = (float*)d_out;                         // [128][256][256]
    float* entropy = coeffs + (size_t)BROWS * NODES * NCH;  // [128][256]
    float* keepf   = entropy + (size_t)BROWS * NODES;       // [128][256] as 0/1 float

    float* part = (float*)d_ws; // [2048 blocks][2][256] = 4 MB

    wht_kernel<<<dim3(BROWS * NGRP), dim3(256), 0, stream>>>(x, coeffs, part);
    finalize_kernel<<<dim3(BROWS * NODES / 64), dim3(256), 0, stream>>>(part, coeffs, entropy, keepf);
}